// Round 2
// baseline (271.381 us; speedup 1.0000x reference)
//
#include <hip/hip_runtime.h>
#include <math.h>

typedef __bf16 bf16_t;
typedef bf16_t bf16x8 __attribute__((ext_vector_type(8)));
typedef float  f32x4  __attribute__((ext_vector_type(4)));

#define PI_F 3.14159265358979323846f

constexpr int H = 64, W = 64, Q = 65536;
constexpr int C = 256, CF = 128;
constexpr int QPB = 32;        // queries per block
constexpr int ROWS = QPB * 4;  // 128 rows (4 ensemble offsets per query)
constexpr int PADC = 264;      // LDS row stride (bf16 elems); 528B -> 2-way-free banks

// ---------------- prep kernels ----------------

// src [Crows][4096] -> dst [4096][Crows]
__global__ void transpose_kernel(const float* __restrict__ src, float* __restrict__ dst, int Crows) {
    __shared__ float tile[32][33];
    int bx = blockIdx.x * 32;  // pixel dim
    int by = blockIdx.y * 32;  // channel dim
    int tx = threadIdx.x & 31;
    int ty = threadIdx.x >> 5;  // 0..7
#pragma unroll
    for (int i = 0; i < 4; i++) {
        tile[ty + i * 8][tx] = src[(by + ty + i * 8) * 4096 + bx + tx];
    }
    __syncthreads();
#pragma unroll
    for (int i = 0; i < 4; i++) {
        dst[(bx + ty + i * 8) * Crows + by + tx] = tile[tx][ty + i * 8];
    }
}

__global__ void cvt_w_kernel(const float* __restrict__ w1, const float* __restrict__ w2,
                             bf16_t* __restrict__ w1b, bf16_t* __restrict__ w2b) {
    int i = blockIdx.x * 256 + threadIdx.x;  // 65536 total
    w1b[i] = (bf16_t)w1[i];
    w2b[i] = (bf16_t)w2[i];
}

// ---------------- fused main kernel ----------------

__global__ __launch_bounds__(512)
void lte_fused_kernel(const float* __restrict__ coefT,   // [4096][256]
                      const float* __restrict__ freqT,   // [4096][128]
                      const bf16_t* __restrict__ w1b,    // [256][256] (out,in)
                      const bf16_t* __restrict__ w2b,
                      const float* __restrict__ img,     // [3][64][64]
                      const float* __restrict__ coord,   // [Q][2]
                      const float* __restrict__ cell,    // [Q][2]
                      const float* __restrict__ wcf,     // [128][2]
                      const float* __restrict__ wph,     // [128][2]
                      const float* __restrict__ b1,
                      const float* __restrict__ b2,
                      const float* __restrict__ w3,      // [3][256]
                      const float* __restrict__ b3,
                      float* __restrict__ out)           // [Q][3]
{
    extern __shared__ char smem[];
    bf16_t* buf    = (bf16_t*)smem;              // [128][264] bf16: X -> h1 -> h2
    float*  w3s    = (float*)(smem + 67584);     // [3][256]
    float*  areaS  = (float*)(smem + 70656);     // [128]
    float*  predsS = (float*)(smem + 71168);     // [128][3]

    const int t    = threadIdx.x;
    const int lane = t & 63;
    const int wv   = t >> 6;     // wave id 0..7 -> column stripe wv*32
    const int l15  = lane & 15;
    const int l16  = lane >> 4;

    // FIX: 768 floats with 512 threads -> strided loop (was `if (t<768)`,
    // leaving w3s[512..767] = uninitialized LDS feeding output channel 2)
    for (int i = t; i < 768; i += 512) w3s[i] = w3[i];

    // ---- stage 1: features -> X (bf16) in LDS ----
    {
        const int row = t >> 2;   // 0..127
        const int t4  = t & 3;    // k-chunk of 32
        const int qL  = row >> 2;
        const int o   = row & 3;
        const int q   = blockIdx.x * QPB + qL;
        const float c0  = coord[q * 2 + 0];
        const float c1  = coord[q * 2 + 1];
        const float rc0 = cell[q * 2 + 0] * (float)H;
        const float rc1 = cell[q * 2 + 1] * (float)W;
        const float vx = (o & 2) ? 1.f : -1.f;
        const float vy = (o & 1) ? 1.f : -1.f;
        const float EPS = 1e-6f;
        float g0 = fminf(fmaxf(c0 + vx * (1.f / H) + EPS, -1.f + EPS), 1.f - EPS);
        float g1 = fminf(fmaxf(c1 + vy * (1.f / W) + EPS, -1.f + EPS), 1.f - EPS);
        int iy = (int)floorf(((g0 + 1.f) * (float)H - 1.f) * 0.5f + 0.5f);
        iy = min(max(iy, 0), H - 1);
        int ix = (int)floorf(((g1 + 1.f) * (float)W - 1.f) * 0.5f + 0.5f);
        ix = min(max(ix, 0), W - 1);
        const float rel0 = (c0 - (-1.f + (2.f * (float)iy + 1.f) / (float)H)) * (float)H;
        const float rel1 = (c1 - (-1.f + (2.f * (float)ix + 1.f) / (float)W)) * (float)W;
        if (t4 == 0) areaS[row] = fabsf(rel0 * rel1) + 1e-9f;
        const int pix = iy * W + ix;
        const float* fq = freqT + pix * CF;
        const float* cf = coefT + pix * C;
#pragma unroll
        for (int c8 = 0; c8 < 4; c8++) {
            const int kb = t4 * 32 + c8 * 8;
            bf16x8 vc, vs;
#pragma unroll
            for (int j = 0; j < 8; j++) {
                const int k = kb + j;
                const float f    = fq[k];
                const float proj = rel0 * wcf[k * 2 + 0] + rel1 * wcf[k * 2 + 1];
                const float ph   = rc0 * wph[k * 2 + 0] + rc1 * wph[k * 2 + 1];
                const float m = f * proj + ph;
                float s, cst;
                __sincosf(PI_F * m, &s, &cst);
                vc[j] = (bf16_t)(cf[k] * cst);
                vs[j] = (bf16_t)(cf[128 + k] * s);
            }
            *(bf16x8*)(buf + row * PADC + kb)       = vc;
            *(bf16x8*)(buf + row * PADC + 128 + kb) = vs;
        }
    }
    __syncthreads();

    // ---- layers 1 & 2: MFMA, each wave owns a 32-col stripe over all 128 rows ----
#pragma unroll 1
    for (int layer = 0; layer < 2; layer++) {
        const bf16_t* Wg = (layer == 0) ? w1b : w2b;
        const float*  bg = (layer == 0) ? b1 : b2;
        f32x4 acc[8][2];
#pragma unroll
        for (int mi = 0; mi < 8; mi++)
#pragma unroll
            for (int nf = 0; nf < 2; nf++) {
                f32x4 z = {0.f, 0.f, 0.f, 0.f};
                acc[mi][nf] = z;
            }
#pragma unroll
        for (int kb = 0; kb < 8; kb++) {
            bf16x8 a[8];
#pragma unroll
            for (int mi = 0; mi < 8; mi++)
                a[mi] = *(bf16x8*)(buf + (mi * 16 + l15) * PADC + kb * 32 + l16 * 8);
            bf16x8 bfr[2];
#pragma unroll
            for (int nf = 0; nf < 2; nf++) {
                const int n = wv * 32 + nf * 16 + l15;
                bfr[nf] = *(const bf16x8*)(Wg + n * 256 + kb * 32 + l16 * 8);
            }
#pragma unroll
            for (int mi = 0; mi < 8; mi++)
#pragma unroll
                for (int nf = 0; nf < 2; nf++)
                    acc[mi][nf] = __builtin_amdgcn_mfma_f32_16x16x32_bf16(a[mi], bfr[nf], acc[mi][nf], 0, 0, 0);
        }
        __syncthreads();  // all reads of buf done
#pragma unroll
        for (int nf = 0; nf < 2; nf++) {
            const int col = wv * 32 + nf * 16 + l15;
            const float bv = bg[col];
#pragma unroll
            for (int mi = 0; mi < 8; mi++)
#pragma unroll
                for (int r = 0; r < 4; r++) {
                    const int row = mi * 16 + l16 * 4 + r;
                    float v = acc[mi][nf][r] + bv;
                    v = fmaxf(v, 0.f);  // relu
                    buf[row * PADC + col] = (bf16_t)v;
                }
        }
        __syncthreads();
    }

    // ---- layer 3: 3 outputs per row, 4 threads/row partial + shuffle reduce ----
    {
        const int row = t >> 2;
        const int t4  = t & 3;
        float p0 = 0.f, p1 = 0.f, p2 = 0.f;
#pragma unroll
        for (int c8 = 0; c8 < 8; c8++) {
            const int c = t4 * 64 + c8 * 8;
            bf16x8 hv = *(bf16x8*)(buf + row * PADC + c);
#pragma unroll
            for (int j = 0; j < 8; j++) {
                const float h = (float)hv[j];
                p0 = fmaf(h, w3s[c + j], p0);
                p1 = fmaf(h, w3s[256 + c + j], p1);
                p2 = fmaf(h, w3s[512 + c + j], p2);
            }
        }
        p0 += __shfl_xor(p0, 1); p0 += __shfl_xor(p0, 2);
        p1 += __shfl_xor(p1, 1); p1 += __shfl_xor(p1, 2);
        p2 += __shfl_xor(p2, 1); p2 += __shfl_xor(p2, 2);
        if (t4 == 0) {
            predsS[row * 3 + 0] = p0 + b3[0];
            predsS[row * 3 + 1] = p1 + b3[1];
            predsS[row * 3 + 2] = p2 + b3[2];
        }
    }
    __syncthreads();

    // ---- combine: area weights (reversed) + bilinear border sample ----
    if (t < QPB) {
        const int qL = t;
        const int q  = blockIdx.x * QPB + qL;
        const int r0 = qL * 4;
        const float a0 = areaS[r0 + 0], a1 = areaS[r0 + 1], a2 = areaS[r0 + 2], a3 = areaS[r0 + 3];
        const float inv = 1.f / (a0 + a1 + a2 + a3);
        const float wgt0 = a3 * inv, wgt1 = a2 * inv, wgt2 = a1 * inv, wgt3 = a0 * inv;
        const float c0 = coord[q * 2 + 0];
        const float c1 = coord[q * 2 + 1];
        float gy = fminf(fmaxf(((c0 + 1.f) * (float)H - 1.f) * 0.5f, 0.f), (float)(H - 1));
        float gx = fminf(fmaxf(((c1 + 1.f) * (float)W - 1.f) * 0.5f, 0.f), (float)(W - 1));
        int y0 = (int)floorf(gy); int x0 = (int)floorf(gx);
        int y1 = min(y0 + 1, H - 1); int x1 = min(x0 + 1, W - 1);
        const float wy = gy - (float)y0, wx = gx - (float)x0;
#pragma unroll
        for (int ch = 0; ch < 3; ch++) {
            const float ret = predsS[(r0 + 0) * 3 + ch] * wgt0 + predsS[(r0 + 1) * 3 + ch] * wgt1
                            + predsS[(r0 + 2) * 3 + ch] * wgt2 + predsS[(r0 + 3) * 3 + ch] * wgt3;
            const float* ip = img + ch * 4096;
            const float v00 = ip[y0 * 64 + x0], v01 = ip[y0 * 64 + x1];
            const float v10 = ip[y1 * 64 + x0], v11 = ip[y1 * 64 + x1];
            const float samp = v00 * (1.f - wy) * (1.f - wx) + v01 * (1.f - wy) * wx
                             + v10 * wy * (1.f - wx) + v11 * wy * wx;
            out[q * 3 + ch] = ret + samp;
        }
    }
}

// ---------------- launch ----------------

extern "C" void kernel_launch(void* const* d_in, const int* in_sizes, int n_in,
                              void* d_out, int out_size, void* d_ws, size_t ws_size,
                              hipStream_t stream) {
    const float* img   = (const float*)d_in[0];
    const float* coef  = (const float*)d_in[1];
    const float* freq  = (const float*)d_in[2];
    const float* coord = (const float*)d_in[3];
    const float* cell  = (const float*)d_in[4];
    const float* wcf   = (const float*)d_in[5];
    const float* wph   = (const float*)d_in[6];
    const float* w1    = (const float*)d_in[7];
    const float* b1    = (const float*)d_in[8];
    const float* w2    = (const float*)d_in[9];
    const float* b2    = (const float*)d_in[10];
    const float* w3    = (const float*)d_in[11];
    const float* b3    = (const float*)d_in[12];
    float* out = (float*)d_out;

    char* ws = (char*)d_ws;
    float*  coefT = (float*)ws;                   // 4096*256*4 = 4,194,304
    float*  freqT = (float*)(ws + 4194304);       // 4096*128*4 = 2,097,152
    bf16_t* w1b   = (bf16_t*)(ws + 6291456);      // 131,072
    bf16_t* w2b   = (bf16_t*)(ws + 6422528);      // 131,072

    transpose_kernel<<<dim3(128, 8), 256, 0, stream>>>(coef, coefT, 256);
    transpose_kernel<<<dim3(128, 4), 256, 0, stream>>>(freq, freqT, 128);
    cvt_w_kernel<<<256, 256, 0, stream>>>(w1, w2, w1b, w2b);

    const size_t ldsBytes = 72704;  // 67584 buf + 3072 w3 + 512 area + 1536 preds
    lte_fused_kernel<<<Q / QPB, 512, ldsBytes, stream>>>(
        coefT, freqT, w1b, w2b, img, coord, cell, wcf, wph, b1, b2, w3, b3, out);
}